// Round 20
// baseline (133.289 us; speedup 1.0000x reference)
//
#include <hip/hip_runtime.h>
#include <hip/hip_bf16.h>
#include <stdint.h>
#include <stddef.h>

// B=2, S=2048, DM=1024, H=16, HD=64.
// out = ((k@Wk+bk) "swapped-attention" (q@Wq+bq, v@Wv+bv)) @ Wo + bo
// scores[b,c,h,q] = kp[b,c,h,:]·qp[b,q,h,:]; softmax over q; out_c = sum_q P*vp[q].
// Softmax is NO-MAX (scores bounded, kp carries log2e): P = exp2(s), l = sum P.
// l is computed ON THE MFMA PIPE (masked-ones A-operand).
// Proj GEMM converts f32 A in-kernel; A-loads are issued DURING the MFMA
// section (T14 async split) so the HBM latency hides under compute.

typedef __attribute__((ext_vector_type(4))) float f32x4;
typedef __attribute__((ext_vector_type(16))) float f32x16;
typedef __attribute__((ext_vector_type(8))) short s16x8;
typedef __attribute__((ext_vector_type(4))) unsigned int u32x4;
typedef __attribute__((ext_vector_type(4))) unsigned short u16x4;

#define DEV static __device__ __forceinline__

DEV unsigned short f2bf(float x) {              // f32 -> bf16 RNE
  unsigned int u = __float_as_uint(x);
  u += 0x7FFF + ((u >> 16) & 1);
  return (unsigned short)(u >> 16);
}
DEV f32x4 mfma16(s16x8 a, s16x8 b, f32x4 c) {
  return __builtin_amdgcn_mfma_f32_16x16x32_bf16(a, b, c, 0, 0, 0);
}
DEV f32x16 mfma32(s16x8 a, s16x8 b, f32x16 c) {
  return __builtin_amdgcn_mfma_f32_32x32x16_bf16(a, b, c, 0, 0, 0);
}
DEV f32x4 fzero() { f32x4 z; z[0]=0.f; z[1]=0.f; z[2]=0.f; z[3]=0.f; return z; }
DEV f32x16 fzero16() {
  f32x16 z;
#pragma unroll
  for (int i = 0; i < 16; ++i) z[i] = 0.f;
  return z;
}
DEV float fexp2(float x) { return __builtin_amdgcn_exp2f(x); }

DEV void gload_lds16(const unsigned short* g, unsigned short* l) {
  __builtin_amdgcn_global_load_lds(
      (const __attribute__((address_space(1))) unsigned int*)g,
      (__attribute__((address_space(3))) unsigned int*)l, 16, 0, 0);
}

#define CVTPK(dst, a, b) \
  asm("v_cvt_pk_bf16_f32 %0, %1, %2" : "=v"(dst) : "v"(a), "v"(b))
#define PSWAP(x, y) \
  asm("v_permlane32_swap_b32 %0, %1" : "+v"(x), "+v"(y))

// ---------------------------------------------------------------------------
// Kernel 0: weight prep only — W[k][n] f32 -> Wt[n][k] bf16. grid (1024,4).
// ---------------------------------------------------------------------------
struct PrepArgs { const float* W[4]; unsigned short* Wt[4]; };

__global__ __launch_bounds__(256) void prep_kernel(PrepArgs a) {
  __shared__ float t[32][33];
  const float* W = a.W[blockIdx.y];
  unsigned short* Wt = a.Wt[blockIdx.y];
  const int n0 = (blockIdx.x & 31) * 32, k0 = (blockIdx.x >> 5) * 32;
  const int tx = threadIdx.x & 31, ty = threadIdx.x >> 5;
#pragma unroll
  for (int i = 0; i < 4; ++i)
    t[ty + i*8][tx] = W[(size_t)(k0 + ty + i*8) * 1024 + n0 + tx];
  __syncthreads();
#pragma unroll
  for (int i = 0; i < 4; ++i)
    Wt[(size_t)(n0 + ty + i*8) * 1024 + k0 + tx] = f2bf(t[tx][ty + i*8]);
}

// ---------------------------------------------------------------------------
// Kernel 2: bf16 GEMM  C[M][1024] = (A @ Wt^T + bias) * scale.
// BM x BN tile, 4 waves (2x2), BK=64, XOR-swizzled LDS, XCD-chunked swizzle.
// AF32=true: A is f32, reg-staged with cvt_pk; the NEXT step's f32 loads
//            are issued after barrier2 (during MFMA) -> latency hidden (T14).
// AF32=false: A is bf16 via global_load_lds (mode 2 reads aout_h layout).
// mode 0: C bf16 row-major; mode 1: C bf16 vpt[b][h][d][s]; mode 2: C f32.
// ---------------------------------------------------------------------------
struct GemArgs {
  const void* A[3];
  const unsigned short* Wt[3];
  const float* bias[3];
  void* C[3];
  int mode[3];
  float scale[3];
};

template<int BM, int BN, bool AF32>
__global__ __launch_bounds__(256) void gemm_kernel(GemArgs g) {
  constexpr int MF = BM / 32;                  // A-frags / staging chunks
  constexpr int NF = BN / 32;
  const int z = blockIdx.z;
  const unsigned short* Wt = g.Wt[z];
  const float* bias = g.bias[z];
  const int mode = g.mode[z];
  const float scale = g.scale[z];
  // XCD-chunked swizzle (bijective: 8 | gridDim.y)
  const int Fb = blockIdx.y * gridDim.x + blockIdx.x;
  const int chunk = gridDim.y >> 3;
  const int myi = (Fb & 7) * chunk + ((Fb >> 3) % chunk);
  const int nxi = (Fb >> 3) / chunk;
  const int m0 = myi * BM, n0 = nxi * BN;
  const int tid = threadIdx.x;
  const int lane = tid & 63, w = tid >> 6;
  const int wm = w >> 1, wn = w & 1;
  const int lg = lane >> 4, lr = lane & 15, lx = lr & 7;

  __shared__ __align__(16) unsigned short As[BM * 64];
  __shared__ __align__(16) unsigned short Bs[BN * 64];

  f32x4 acc[MF][NF];
#pragma unroll
  for (int i = 0; i < MF; ++i)
#pragma unroll
    for (int j = 0; j < NF; ++j) acc[i][j] = fzero();

  // A staging pointers
  const float* srcAf[MF];
  const unsigned short* srcA[MF];
  unsigned short* dstA[MF];
#pragma unroll
  for (int c = 0; c < MF; ++c) {
    int n = c*256 + tid, row = n >> 3, cg = (n & 7) ^ (row & 7);
    int s = m0 + row;
    if constexpr (AF32) {
      srcAf[c] = (const float*)g.A[z] + (size_t)s * 1024 + cg * 8;
      srcA[c] = nullptr;
    } else {
      size_t abase = (mode == 2)
          ? ((size_t)((s >> 11) * 16) * 2048 + (s & 2047)) * 64 + cg * 8
          : (size_t)s * 1024 + cg * 8;
      srcA[c] = (const unsigned short*)g.A[z] + abase;
      srcAf[c] = nullptr;
    }
    dstA[c] = &As[n * 8];
  }
  const int aStep = (!AF32 && mode == 2) ? 2048 * 64 : 64;
  const unsigned short* srcB[NF]; unsigned short* dstB[NF];
#pragma unroll
  for (int c = 0; c < NF; ++c) {
    int n = c*256 + tid, row = n >> 3, cg = (n & 7) ^ (row & 7);
    srcB[c] = Wt + (size_t)(n0 + row) * 1024 + cg * 8;
    dstB[c] = &Bs[n * 8];
  }

  // T14 preload: va(0) issued before the loop.
  f32x4 va[AF32 ? MF : 1][2];
  if constexpr (AF32) {
#pragma unroll
    for (int c = 0; c < MF; ++c) {
      va[c][0] = *(const f32x4*)(srcAf[c]);
      va[c][1] = *(const f32x4*)(srcAf[c] + 4);
      srcAf[c] += 64;
    }
  }

  for (int it = 0; it < 16; ++it) {
    __syncthreads();                           // barrier1: prev reads done
    if constexpr (AF32) {
#pragma unroll
      for (int c = 0; c < MF; ++c) {
        u32x4 pk;
        CVTPK(pk[0], va[c][0][0], va[c][0][1]);
        CVTPK(pk[1], va[c][0][2], va[c][0][3]);
        CVTPK(pk[2], va[c][1][0], va[c][1][1]);
        CVTPK(pk[3], va[c][1][2], va[c][1][3]);
        *(u32x4*)dstA[c] = pk;
      }
#pragma unroll
      for (int c = 0; c < NF; ++c) { gload_lds16(srcB[c], dstB[c]); srcB[c] += 64; }
    } else {
#pragma unroll
      for (int c = 0; c < MF; ++c) { gload_lds16(srcA[c], dstA[c]); srcA[c] += aStep; }
#pragma unroll
      for (int c = 0; c < NF; ++c) { gload_lds16(srcB[c], dstB[c]); srcB[c] += 64; }
    }
    __syncthreads();                           // barrier2: staging visible

    if constexpr (AF32) {
      // issue NEXT step's f32 loads now — they drain at the next barrier1,
      // i.e. behind the whole ds_read+MFMA section (latency hidden).
      if (it + 1 < 16) {
#pragma unroll
        for (int c = 0; c < MF; ++c) {
          va[c][0] = *(const f32x4*)(srcAf[c]);
          va[c][1] = *(const f32x4*)(srcAf[c] + 4);
          srcAf[c] += 64;
        }
      }
    }

    s16x8 af[2][MF], bf[2][NF];
#pragma unroll
    for (int ks = 0; ks < 2; ++ks) {
#pragma unroll
      for (int mf = 0; mf < MF; ++mf) {
        int row = wm*(BM/2) + mf*16 + lr;
        af[ks][mf] = *(const s16x8*)&As[row*64 + ((ks*4 + lg) ^ lx) * 8];
      }
#pragma unroll
      for (int nf = 0; nf < NF; ++nf) {
        int row = wn*(BN/2) + nf*16 + lr;
        bf[ks][nf] = *(const s16x8*)&Bs[row*64 + ((ks*4 + lg) ^ lx) * 8];
      }
    }
#pragma unroll
    for (int mf = 0; mf < MF; ++mf)
#pragma unroll
      for (int nf = 0; nf < NF; ++nf) {
        acc[mf][nf] = mfma16(af[0][mf], bf[0][nf], acc[mf][nf]);
        acc[mf][nf] = mfma16(af[1][mf], bf[1][nf], acc[mf][nf]);
      }
  }

#pragma unroll
  for (int nf = 0; nf < NF; ++nf) {
    const int colg = n0 + wn*(BN/2) + nf*16 + lr;
    const float bi = bias[colg];
#pragma unroll
    for (int mf = 0; mf < MF; ++mf) {
      const int rowg0 = m0 + wm*(BM/2) + mf*16 + lg*4;
      if (mode == 0) {
        unsigned short* o = (unsigned short*)g.C[z];
#pragma unroll
        for (int r = 0; r < 4; ++r)
          o[(size_t)(rowg0 + r) * 1024 + colg] = f2bf((acc[mf][nf][r] + bi) * scale);
      } else if (mode == 1) {
        const int hh = colg >> 6, d = colg & 63;
        const int bb2 = rowg0 >> 11, s = rowg0 & 2047;
        u16x4 pk;
#pragma unroll
        for (int r = 0; r < 4; ++r) pk[r] = f2bf(acc[mf][nf][r] + bi);
        *(u16x4*)((unsigned short*)g.C[z] + ((size_t)((bb2*16 + hh)*64 + d)) * 2048 + s) = pk;
      } else {
        float* o = (float*)g.C[z];
#pragma unroll
        for (int r = 0; r < 4; ++r)
          o[(size_t)(rowg0 + r) * 1024 + colg] = acc[mf][nf][r] + bi;
      }
    }
  }
}

// ---------------------------------------------------------------------------
// Kernel 3: flash attention, swapped-operand 32x32x16 MFMA, LDS-staged K/V,
// NO-MAX softmax, 2 c-groups per wave (ILP), in-block j-split x2.
// l on the MFMA pipe via masked-ones A-operand (r17-validated).
// Grid 512 = 16 cblk x 32 bh, chunked XCD swizzle (4 bh/XCD => 2MB in L2).
// ---------------------------------------------------------------------------
__global__ __launch_bounds__(256) void attn_kernel(
    const unsigned short* __restrict__ kp, const unsigned short* __restrict__ qp,
    const unsigned short* __restrict__ vpt, unsigned short* __restrict__ aout) {
  const int F = blockIdx.x;                       // [0,512)
  const int swz = (F & 7) * 64 + (F >> 3);        // XCD x -> [64x, 64x+64)
  const int bh = swz >> 4, cblk = swz & 15;
  const int b = bh >> 4, h = bh & 15;
  const int c0 = cblk * 128;
  const int tid = threadIdx.x, lane = tid & 63, w = tid >> 6;
  const int cg = w & 1, jg = w >> 1;
  const int ln = lane & 31, hh = lane >> 5;

  __shared__ __align__(16) unsigned short qa_lds[2][2][2048];  // [buf][jhalf] 16KB
  __shared__ __align__(16) unsigned short vb_lds[2][2][2048];  // 16KB
  __shared__ float lbuf[2][2][64];                             // merge l

  // staging: thread stages one 16B chunk per (qa,vb) x (jhalf) per tile.
  const int srow = tid >> 3, sp = tid & 7, sl = sp ^ (srow & 7);
  const unsigned short* qsrc0 =
      qp + (size_t)(b*2048 + srow) * 1024 + h*64 + sl*8;
  const unsigned short* qsrc1 = qsrc0 + (size_t)1024 * 1024;
  const int sd = srow + 32*(sl >> 2), sjc = sl & 3;
  const unsigned short* vsrc0 =
      vpt + ((size_t)((b*16 + h)*64) + sd) * 2048 + sjc*8;
  const unsigned short* vsrc1 = vsrc0 + 1024;

  // kb: QK B-operand, two c-groups: cA = c0+cg*64+ln, cB = cA+32
  s16x8 kbA[4], kbB[4];
  {
    const unsigned short* krowA =
        kp + (size_t)(b*2048 + c0 + cg*64 + ln) * 1024 + h*64 + hh*8;
    const unsigned short* krowB = krowA + 32 * 1024;
#pragma unroll
    for (int s = 0; s < 4; ++s) {
      kbA[s] = *(const s16x8*)(krowA + s*16);
      kbB[s] = *(const s16x8*)(krowB + s*16);
    }
  }

  // masked-ones A-operands for the l-MFMA (A row = ln)
  s16x8 onesA, onesB;
  {
    const short oa = (short)((ln < 16) ? 0x3F80 : 0);
    const short ob = (short)((ln < 16) ? 0 : 0x3F80);
#pragma unroll
    for (int i = 0; i < 8; ++i) { onesA[i] = oa; onesB[i] = ob; }
  }

  f32x16 accA0 = fzero16(), accA1 = fzero16();
  f32x16 accB0 = fzero16(), accB1 = fzero16();
  f32x16 lacc = fzero16();

  // prologue: stage tile 0 (both j-halves) into buffer 0
  gload_lds16(qsrc0, &qa_lds[0][0][tid*8]);
  gload_lds16(qsrc1, &qa_lds[0][1][tid*8]);
  gload_lds16(vsrc0, &vb_lds[0][0][tid*8]);
  gload_lds16(vsrc1, &vb_lds[0][1][tid*8]);
  qsrc0 += 32*1024; qsrc1 += 32*1024; vsrc0 += 32; vsrc1 += 32;
  __syncthreads();

  for (int jt = 0; jt < 32; ++jt) {
    const int cur = jt & 1;
    if (jt + 1 < 32) {
      gload_lds16(qsrc0, &qa_lds[cur^1][0][tid*8]);
      gload_lds16(qsrc1, &qa_lds[cur^1][1][tid*8]);
      gload_lds16(vsrc0, &vb_lds[cur^1][0][tid*8]);
      gload_lds16(vsrc1, &vb_lds[cur^1][1][tid*8]);
      qsrc0 += 32*1024; qsrc1 += 32*1024; vsrc0 += 32; vsrc1 += 32;
    }

    // qa fragments (shared by both c-groups): row = j = ln, chunk 2s+hh
    s16x8 qa0, qa1, qa2, qa3;
    {
      const unsigned short* base = &qa_lds[cur][jg][0];
      qa0 = *(const s16x8*)&base[(ln*8 + ((0 + hh) ^ (ln & 7)))*8];
      qa1 = *(const s16x8*)&base[(ln*8 + ((2 + hh) ^ (ln & 7)))*8];
      qa2 = *(const s16x8*)&base[(ln*8 + ((4 + hh) ^ (ln & 7)))*8];
      qa3 = *(const s16x8*)&base[(ln*8 + ((6 + hh) ^ (ln & 7)))*8];
    }
    // vb fragments (shared): l = dhalf*4 + jhalf*2 + hh
    s16x8 vb0, vb1, vb2, vb3;
    {
      const unsigned short* base = &vb_lds[cur][jg][0];
      vb0 = *(const s16x8*)&base[(ln*8 + ((0 + hh) ^ (ln & 7)))*8];
      vb1 = *(const s16x8*)&base[(ln*8 + ((2 + hh) ^ (ln & 7)))*8];
      vb2 = *(const s16x8*)&base[(ln*8 + ((4 + hh) ^ (ln & 7)))*8];
      vb3 = *(const s16x8*)&base[(ln*8 + ((6 + hh) ^ (ln & 7)))*8];
    }

    f32x16 scA = fzero16(), scB = fzero16();
    __builtin_amdgcn_s_setprio(1);
    scA = mfma32(qa0, kbA[0], scA); scA = mfma32(qa1, kbA[1], scA);
    scA = mfma32(qa2, kbA[2], scA); scA = mfma32(qa3, kbA[3], scA);
    scB = mfma32(qa0, kbB[0], scB); scB = mfma32(qa1, kbB[1], scB);
    scB = mfma32(qa2, kbB[2], scB); scB = mfma32(qa3, kbB[3], scB);
    __builtin_amdgcn_s_setprio(0);

#define SOFTMAX_PV(SC, ONES, ACC0, ACC1)                                      \
  {                                                                           \
    _Pragma("unroll")                                                         \
    for (int r = 0; r < 16; ++r) SC[r] = fexp2(SC[r]);                        \
    unsigned int a0, a1, b0, b1;                                              \
    u32x4 wv; s16x8 pa0, pa1;                                                 \
    CVTPK(a0, SC[0], SC[1]);  CVTPK(b0, SC[4], SC[5]);  PSWAP(a0, b0);        \
    CVTPK(a1, SC[2], SC[3]);  CVTPK(b1, SC[6], SC[7]);  PSWAP(a1, b1);        \
    wv[0] = a0; wv[1] = a1; wv[2] = b0; wv[3] = b1;                           \
    pa0 = __builtin_bit_cast(s16x8, wv);                                      \
    CVTPK(a0, SC[8], SC[9]);  CVTPK(b0, SC[12], SC[13]); PSWAP(a0, b0);       \
    CVTPK(a1, SC[10], SC[11]); CVTPK(b1, SC[14], SC[15]); PSWAP(a1, b1);      \
    wv[0] = a0; wv[1] = a1; wv[2] = b0; wv[3] = b1;                           \
    pa1 = __builtin_bit_cast(s16x8, wv);                                      \
    __builtin_amdgcn_s_setprio(1);                                            \
    lacc = mfma32(ONES, pa0, lacc);                                           \
    lacc = mfma32(ONES, pa1, lacc);                                           \
    ACC0 = mfma32(vb0, pa0, ACC0);                                            \
    ACC0 = mfma32(vb1, pa1, ACC0);                                            \
    ACC1 = mfma32(vb2, pa0, ACC1);                                            \
    ACC1 = mfma32(vb3, pa1, ACC1);                                            \
    __builtin_amdgcn_s_setprio(0);                                            \
  }

    SOFTMAX_PV(scA, onesA, accA0, accA1);
    SOFTMAX_PV(scB, onesB, accB0, accB1);
#undef SOFTMAX_PV

    __syncthreads();
  }

  // l extraction: lacc[0] = group A, lacc[8] = group B (halves pre-summed).
  float lA = lacc[0], lB = lacc[8];

  // merge j-partials: plain adds (no-max softmax => exact).
  float* mrg = cg ? (float*)&vb_lds[0][0][0] : (float*)&qa_lds[0][0][0];
  if (jg == 1) {
    lbuf[cg][0][lane] = lA; lbuf[cg][1][lane] = lB;
#pragma unroll
    for (int r = 0; r < 16; ++r) {
      mrg[(r)*64 + lane]      = accA0[r];
      mrg[(16 + r)*64 + lane] = accA1[r];
      mrg[(32 + r)*64 + lane] = accB0[r];
      mrg[(48 + r)*64 + lane] = accB1[r];
    }
  }
  __syncthreads();
  if (jg == 0) {
    lA += lbuf[cg][0][lane]; lB += lbuf[cg][1][lane];
#pragma unroll
    for (int r = 0; r < 16; ++r) {
      accA0[r] += mrg[(r)*64 + lane];
      accA1[r] += mrg[(16 + r)*64 + lane];
      accB0[r] += mrg[(32 + r)*64 + lane];
      accB1[r] += mrg[(48 + r)*64 + lane];
    }
    const float invA = 1.0f / lA, invB = 1.0f / lB;
    unsigned short* obaseA =
        aout + ((size_t)bh * 2048 + c0 + cg*64 + ln) * 64 + hh * 4;
    unsigned short* obaseB = obaseA + 32 * 64;
#pragma unroll
    for (int dt = 0; dt < 2; ++dt)
#pragma unroll
      for (int rq = 0; rq < 4; ++rq) {
        u16x4 pkA, pkB;
#pragma unroll
        for (int i = 0; i < 4; ++i) {
          const int reg = rq*4 + i;
          pkA[i] = f2bf(((dt == 0) ? accA0[reg] : accA1[reg]) * invA);
          pkB[i] = f2bf(((dt == 0) ? accB0[reg] : accB1[reg]) * invB);
        }
        *(u16x4*)(obaseA + dt*32 + rq*8) = pkA;
        *(u16x4*)(obaseB + dt*32 + rq*8) = pkB;
      }
  }
}

// ---------------------------------------------------------------------------
extern "C" void kernel_launch(void* const* d_in, const int* in_sizes, int n_in,
                              void* d_out, int out_size, void* d_ws, size_t ws_size,
                              hipStream_t stream) {
  (void)in_sizes; (void)n_in; (void)out_size; (void)ws_size;
  const float* k  = (const float*)d_in[0];
  const float* q  = (const float*)d_in[1];
  const float* v  = (const float*)d_in[2];
  const float* Wk = (const float*)d_in[3];
  const float* bk = (const float*)d_in[4];
  const float* Wq = (const float*)d_in[5];
  const float* bq = (const float*)d_in[6];
  const float* Wv = (const float*)d_in[7];
  const float* bv = (const float*)d_in[8];
  const float* Wo = (const float*)d_in[9];
  const float* bo = (const float*)d_in[10];

  char* ws = (char*)d_ws;
  const size_t MB = 1024 * 1024;
  unsigned short* Wkt = (unsigned short*)(ws + 0*MB);
  unsigned short* Wqt = (unsigned short*)(ws + 2*MB);
  unsigned short* Wvt = (unsigned short*)(ws + 4*MB);
  unsigned short* Wot = (unsigned short*)(ws + 6*MB);
  unsigned short* kp  = (unsigned short*)(ws + 8*MB);
  unsigned short* qp  = (unsigned short*)(ws + 16*MB);
  unsigned short* vpt = (unsigned short*)(ws + 24*MB);
  unsigned short* aoutb = (unsigned short*)(ws + 40*MB);  // [b][h][s][64] bf16

  PrepArgs pa;
  pa.W[0] = Wk; pa.W[1] = Wq; pa.W[2] = Wv; pa.W[3] = Wo;
  pa.Wt[0] = Wkt; pa.Wt[1] = Wqt; pa.Wt[2] = Wvt; pa.Wt[3] = Wot;
  prep_kernel<<<dim3(1024, 4), 256, 0, stream>>>(pa);

  GemArgs gp;
  gp.A[0] = k; gp.A[1] = q; gp.A[2] = v;        // f32, converted in-kernel
  gp.Wt[0] = Wkt; gp.Wt[1] = Wqt; gp.Wt[2] = Wvt;
  gp.bias[0] = bk; gp.bias[1] = bq; gp.bias[2] = bv;
  gp.C[0] = kp; gp.C[1] = qp; gp.C[2] = vpt;
  gp.mode[0] = 0; gp.mode[1] = 0; gp.mode[2] = 1;
  gp.scale[0] = 1.4426950408889634f;   // log2(e) folded into kp
  gp.scale[1] = 1.0f; gp.scale[2] = 1.0f;
  gemm_kernel<128, 128, true><<<dim3(8, 32, 3), 256, 0, stream>>>(gp);

  attn_kernel<<<dim3(512), 256, 0, stream>>>(kp, qp, vpt, aoutb);

  GemArgs gf;
  gf.A[0] = aoutb; gf.A[1] = aoutb; gf.A[2] = aoutb;
  gf.Wt[0] = Wot; gf.Wt[1] = Wot; gf.Wt[2] = Wot;
  gf.bias[0] = bo; gf.bias[1] = bo; gf.bias[2] = bo;
  gf.C[0] = d_out; gf.C[1] = d_out; gf.C[2] = d_out;
  gf.mode[0] = 2; gf.mode[1] = 2; gf.mode[2] = 2;
  gf.scale[0] = 1.0f; gf.scale[1] = 1.0f; gf.scale[2] = 1.0f;
  gemm_kernel<64, 64, false><<<dim3(16, 64, 1), 256, 0, stream>>>(gf);
}

// Round 21
// 122.818 us; speedup vs baseline: 1.0853x; 1.0853x over previous
//
#include <hip/hip_runtime.h>
#include <hip/hip_bf16.h>
#include <stdint.h>
#include <stddef.h>

// B=2, S=2048, DM=1024, H=16, HD=64.
// out = ((k@Wk+bk) "swapped-attention" (q@Wq+bq, v@Wv+bv)) @ Wo + bo
// scores[b,c,h,q] = kp[b,c,h,:]·qp[b,q,h,:]; softmax over q; out_c = sum_q P*vp[q].
// Softmax is NO-MAX (scores bounded, kp carries log2e): P = exp2(s), l = sum P.
// l is computed ON THE MFMA PIPE (masked-ones A-operand).
// (r18 configuration — best verified: 123.2 us.)

typedef __attribute__((ext_vector_type(4))) float f32x4;
typedef __attribute__((ext_vector_type(16))) float f32x16;
typedef __attribute__((ext_vector_type(8))) short s16x8;
typedef __attribute__((ext_vector_type(4))) unsigned int u32x4;
typedef __attribute__((ext_vector_type(4))) unsigned short u16x4;

#define DEV static __device__ __forceinline__

DEV unsigned short f2bf(float x) {              // f32 -> bf16 RNE
  unsigned int u = __float_as_uint(x);
  u += 0x7FFF + ((u >> 16) & 1);
  return (unsigned short)(u >> 16);
}
DEV f32x4 mfma16(s16x8 a, s16x8 b, f32x4 c) {
  return __builtin_amdgcn_mfma_f32_16x16x32_bf16(a, b, c, 0, 0, 0);
}
DEV f32x16 mfma32(s16x8 a, s16x8 b, f32x16 c) {
  return __builtin_amdgcn_mfma_f32_32x32x16_bf16(a, b, c, 0, 0, 0);
}
DEV f32x4 fzero() { f32x4 z; z[0]=0.f; z[1]=0.f; z[2]=0.f; z[3]=0.f; return z; }
DEV f32x16 fzero16() {
  f32x16 z;
#pragma unroll
  for (int i = 0; i < 16; ++i) z[i] = 0.f;
  return z;
}
DEV float fexp2(float x) { return __builtin_amdgcn_exp2f(x); }

DEV void gload_lds16(const unsigned short* g, unsigned short* l) {
  __builtin_amdgcn_global_load_lds(
      (const __attribute__((address_space(1))) unsigned int*)g,
      (__attribute__((address_space(3))) unsigned int*)l, 16, 0, 0);
}

#define CVTPK(dst, a, b) \
  asm("v_cvt_pk_bf16_f32 %0, %1, %2" : "=v"(dst) : "v"(a), "v"(b))
#define PSWAP(x, y) \
  asm("v_permlane32_swap_b32 %0, %1" : "+v"(x), "+v"(y))

// ---------------------------------------------------------------------------
// Kernel 0: merged prep — planes 0-2: f32->bf16 convert (k,q,v, 32B/thread);
// planes 3-6: weight transpose W[k][n] -> Wt[n][k] bf16.
// grid (2048, 7) x 256 thr.
// ---------------------------------------------------------------------------
struct PrepArgs {
  const float* x[3]; unsigned short* y[3];
  const float* W[4]; unsigned short* Wt[4];
};

__global__ __launch_bounds__(256) void prep_kernel(PrepArgs a) {
  __shared__ float t[32][33];
  const int plane = blockIdx.y;
  if (plane < 3) {
    const float* x = a.x[plane];
    unsigned short* y = a.y[plane];
    const int i = blockIdx.x * 256 + threadIdx.x;   // 8 elems each
    f32x4 v0 = ((const f32x4*)x)[2*i];
    f32x4 v1 = ((const f32x4*)x)[2*i + 1];
    u16x4 o0, o1;
#pragma unroll
    for (int j = 0; j < 4; ++j) { o0[j] = f2bf(v0[j]); o1[j] = f2bf(v1[j]); }
    ((u16x4*)y)[2*i] = o0;
    ((u16x4*)y)[2*i + 1] = o1;
  } else {
    if (blockIdx.x >= 1024) return;
    const float* W = a.W[plane - 3];
    unsigned short* Wt = a.Wt[plane - 3];
    const int n0 = (blockIdx.x & 31) * 32, k0 = (blockIdx.x >> 5) * 32;
    const int tx = threadIdx.x & 31, ty = threadIdx.x >> 5;
#pragma unroll
    for (int i = 0; i < 4; ++i)
      t[ty + i*8][tx] = W[(size_t)(k0 + ty + i*8) * 1024 + n0 + tx];
    __syncthreads();
#pragma unroll
    for (int i = 0; i < 4; ++i)
      Wt[(size_t)(n0 + ty + i*8) * 1024 + k0 + tx] = f2bf(t[tx][ty + i*8]);
  }
}

// ---------------------------------------------------------------------------
// Kernel 2: bf16 GEMM  C[M][1024] = (A[M][1024] @ Wt^T + bias) * scale.
// BM x BN tile, 4 waves (2x2, wave tile BM/2 x BN/2), BK=64,
// global_load_lds staging (pre-swizzled source), XOR-swizzled LDS.
// XCD-chunked block swizzle (bijective when 8 | grid).
// mode 0: C bf16 row-major; mode 1: C bf16 vpt[b][h][d][s]; mode 2: C f32,
//         A read from aout_h layout [b][h][s][64].
// Final GEMM uses <64,64>: grid 1024 = 4 blocks/CU (latency-bound regime).
// ---------------------------------------------------------------------------
struct GemArgs {
  const unsigned short* A[3];
  const unsigned short* Wt[3];
  const float* bias[3];
  void* C[3];
  int mode[3];
  float scale[3];
};

template<int BM, int BN>
__global__ __launch_bounds__(256) void gemm_kernel(GemArgs g) {
  constexpr int MF = BM / 32;                  // A-frags per wave
  constexpr int NF = BN / 32;                  // B-frags per wave
  constexpr int NB = BN / 32;                  // B staging chunks per thread
  const int z = blockIdx.z;
  const unsigned short* A  = g.A[z];
  const unsigned short* Wt = g.Wt[z];
  const float* bias = g.bias[z];
  const int mode = g.mode[z];
  const float scale = g.scale[z];
  // XCD-chunked swizzle
  const int Fb = blockIdx.y * gridDim.x + blockIdx.x;
  const int chunk = gridDim.y >> 3;
  const int myi = (Fb & 7) * chunk + ((Fb >> 3) % chunk);
  const int nxi = (Fb >> 3) / chunk;
  const int m0 = myi * BM, n0 = nxi * BN;
  const int tid = threadIdx.x;
  const int lane = tid & 63, w = tid >> 6;
  const int wm = w >> 1, wn = w & 1;
  const int lg = lane >> 4, lr = lane & 15, lx = lr & 7;

  __shared__ __align__(16) unsigned short As[BM * 64];
  __shared__ __align__(16) unsigned short Bs[BN * 64];

  f32x4 acc[MF][NF];
#pragma unroll
  for (int i = 0; i < MF; ++i)
#pragma unroll
    for (int j = 0; j < NF; ++j) acc[i][j] = fzero();

  const int aStep = (mode == 2) ? 2048 * 64 : 64;
  const unsigned short* srcA[MF]; unsigned short* dstA[MF];
#pragma unroll
  for (int c = 0; c < MF; ++c) {
    int n = c*256 + tid, row = n >> 3, cg = (n & 7) ^ (row & 7);
    int s = m0 + row;
    size_t abase = (mode == 2)
        ? ((size_t)((s >> 11) * 16) * 2048 + (s & 2047)) * 64 + cg * 8
        : (size_t)s * 1024 + cg * 8;
    srcA[c] = A + abase;
    dstA[c] = &As[n * 8];
  }
  const unsigned short* srcB[NB]; unsigned short* dstB[NB];
#pragma unroll
  for (int c = 0; c < NB; ++c) {
    int n = c*256 + tid, row = n >> 3, cg = (n & 7) ^ (row & 7);
    srcB[c] = Wt + (size_t)(n0 + row) * 1024 + cg * 8;
    dstB[c] = &Bs[n * 8];
  }

  for (int it = 0; it < 16; ++it) {
    __syncthreads();
#pragma unroll
    for (int c = 0; c < MF; ++c) { gload_lds16(srcA[c], dstA[c]); srcA[c] += aStep; }
#pragma unroll
    for (int c = 0; c < NB; ++c) { gload_lds16(srcB[c], dstB[c]); srcB[c] += 64; }
    __syncthreads();

    s16x8 af[2][MF], bf[2][NF];
#pragma unroll
    for (int ks = 0; ks < 2; ++ks) {
#pragma unroll
      for (int mf = 0; mf < MF; ++mf) {
        int row = wm*(BM/2) + mf*16 + lr;
        af[ks][mf] = *(const s16x8*)&As[row*64 + ((ks*4 + lg) ^ lx) * 8];
      }
#pragma unroll
      for (int nf = 0; nf < NF; ++nf) {
        int row = wn*(BN/2) + nf*16 + lr;
        bf[ks][nf] = *(const s16x8*)&Bs[row*64 + ((ks*4 + lg) ^ lx) * 8];
      }
    }
#pragma unroll
    for (int mf = 0; mf < MF; ++mf)
#pragma unroll
      for (int nf = 0; nf < NF; ++nf) {
        acc[mf][nf] = mfma16(af[0][mf], bf[0][nf], acc[mf][nf]);
        acc[mf][nf] = mfma16(af[1][mf], bf[1][nf], acc[mf][nf]);
      }
  }

#pragma unroll
  for (int nf = 0; nf < NF; ++nf) {
    const int colg = n0 + wn*(BN/2) + nf*16 + lr;
    const float bi = bias[colg];
#pragma unroll
    for (int mf = 0; mf < MF; ++mf) {
      const int rowg0 = m0 + wm*(BM/2) + mf*16 + lg*4;
      if (mode == 0) {
        unsigned short* o = (unsigned short*)g.C[z];
#pragma unroll
        for (int r = 0; r < 4; ++r)
          o[(size_t)(rowg0 + r) * 1024 + colg] = f2bf((acc[mf][nf][r] + bi) * scale);
      } else if (mode == 1) {
        const int hh = colg >> 6, d = colg & 63;
        const int bb2 = rowg0 >> 11, s = rowg0 & 2047;
        u16x4 pk;
#pragma unroll
        for (int r = 0; r < 4; ++r) pk[r] = f2bf(acc[mf][nf][r] + bi);
        *(u16x4*)((unsigned short*)g.C[z] + ((size_t)((bb2*16 + hh)*64 + d)) * 2048 + s) = pk;
      } else {
        float* o = (float*)g.C[z];
#pragma unroll
        for (int r = 0; r < 4; ++r)
          o[(size_t)(rowg0 + r) * 1024 + colg] = acc[mf][nf][r] + bi;
      }
    }
  }
}

// ---------------------------------------------------------------------------
// Kernel 3: flash attention, swapped-operand 32x32x16 MFMA, LDS-staged K/V,
// NO-MAX softmax, 2 c-groups per wave (ILP), in-block j-split x2.
// l on the MFMA pipe via masked-ones A-operand (r17-validated).
// Grid 512 = 16 cblk x 32 bh, chunked XCD swizzle (4 bh/XCD => 2MB in L2).
// ---------------------------------------------------------------------------
__global__ __launch_bounds__(256) void attn_kernel(
    const unsigned short* __restrict__ kp, const unsigned short* __restrict__ qp,
    const unsigned short* __restrict__ vpt, unsigned short* __restrict__ aout) {
  const int F = blockIdx.x;                       // [0,512)
  const int swz = (F & 7) * 64 + (F >> 3);        // XCD x -> [64x, 64x+64)
  const int bh = swz >> 4, cblk = swz & 15;
  const int b = bh >> 4, h = bh & 15;
  const int c0 = cblk * 128;
  const int tid = threadIdx.x, lane = tid & 63, w = tid >> 6;
  const int cg = w & 1, jg = w >> 1;
  const int ln = lane & 31, hh = lane >> 5;

  __shared__ __align__(16) unsigned short qa_lds[2][2][2048];  // [buf][jhalf] 16KB
  __shared__ __align__(16) unsigned short vb_lds[2][2][2048];  // 16KB
  __shared__ float lbuf[2][2][64];                             // merge l

  // staging: thread stages one 16B chunk per (qa,vb) x (jhalf) per tile.
  const int srow = tid >> 3, sp = tid & 7, sl = sp ^ (srow & 7);
  const unsigned short* qsrc0 =
      qp + (size_t)(b*2048 + srow) * 1024 + h*64 + sl*8;
  const unsigned short* qsrc1 = qsrc0 + (size_t)1024 * 1024;
  const int sd = srow + 32*(sl >> 2), sjc = sl & 3;
  const unsigned short* vsrc0 =
      vpt + ((size_t)((b*16 + h)*64) + sd) * 2048 + sjc*8;
  const unsigned short* vsrc1 = vsrc0 + 1024;

  // kb: QK B-operand, two c-groups: cA = c0+cg*64+ln, cB = cA+32
  s16x8 kbA[4], kbB[4];
  {
    const unsigned short* krowA =
        kp + (size_t)(b*2048 + c0 + cg*64 + ln) * 1024 + h*64 + hh*8;
    const unsigned short* krowB = krowA + 32 * 1024;
#pragma unroll
    for (int s = 0; s < 4; ++s) {
      kbA[s] = *(const s16x8*)(krowA + s*16);
      kbB[s] = *(const s16x8*)(krowB + s*16);
    }
  }

  // masked-ones A-operands for the l-MFMA (A row = ln)
  s16x8 onesA, onesB;
  {
    const short oa = (short)((ln < 16) ? 0x3F80 : 0);
    const short ob = (short)((ln < 16) ? 0 : 0x3F80);
#pragma unroll
    for (int i = 0; i < 8; ++i) { onesA[i] = oa; onesB[i] = ob; }
  }

  f32x16 accA0 = fzero16(), accA1 = fzero16();
  f32x16 accB0 = fzero16(), accB1 = fzero16();
  f32x16 lacc = fzero16();

  // prologue: stage tile 0 (both j-halves) into buffer 0
  gload_lds16(qsrc0, &qa_lds[0][0][tid*8]);
  gload_lds16(qsrc1, &qa_lds[0][1][tid*8]);
  gload_lds16(vsrc0, &vb_lds[0][0][tid*8]);
  gload_lds16(vsrc1, &vb_lds[0][1][tid*8]);
  qsrc0 += 32*1024; qsrc1 += 32*1024; vsrc0 += 32; vsrc1 += 32;
  __syncthreads();

  for (int jt = 0; jt < 32; ++jt) {
    const int cur = jt & 1;
    if (jt + 1 < 32) {
      gload_lds16(qsrc0, &qa_lds[cur^1][0][tid*8]);
      gload_lds16(qsrc1, &qa_lds[cur^1][1][tid*8]);
      gload_lds16(vsrc0, &vb_lds[cur^1][0][tid*8]);
      gload_lds16(vsrc1, &vb_lds[cur^1][1][tid*8]);
      qsrc0 += 32*1024; qsrc1 += 32*1024; vsrc0 += 32; vsrc1 += 32;
    }

    // qa fragments (shared by both c-groups): row = j = ln, chunk 2s+hh
    s16x8 qa0, qa1, qa2, qa3;
    {
      const unsigned short* base = &qa_lds[cur][jg][0];
      qa0 = *(const s16x8*)&base[(ln*8 + ((0 + hh) ^ (ln & 7)))*8];
      qa1 = *(const s16x8*)&base[(ln*8 + ((2 + hh) ^ (ln & 7)))*8];
      qa2 = *(const s16x8*)&base[(ln*8 + ((4 + hh) ^ (ln & 7)))*8];
      qa3 = *(const s16x8*)&base[(ln*8 + ((6 + hh) ^ (ln & 7)))*8];
    }
    // vb fragments (shared): l = dhalf*4 + jhalf*2 + hh
    s16x8 vb0, vb1, vb2, vb3;
    {
      const unsigned short* base = &vb_lds[cur][jg][0];
      vb0 = *(const s16x8*)&base[(ln*8 + ((0 + hh) ^ (ln & 7)))*8];
      vb1 = *(const s16x8*)&base[(ln*8 + ((2 + hh) ^ (ln & 7)))*8];
      vb2 = *(const s16x8*)&base[(ln*8 + ((4 + hh) ^ (ln & 7)))*8];
      vb3 = *(const s16x8*)&base[(ln*8 + ((6 + hh) ^ (ln & 7)))*8];
    }

    f32x16 scA = fzero16(), scB = fzero16();
    __builtin_amdgcn_s_setprio(1);
    scA = mfma32(qa0, kbA[0], scA); scA = mfma32(qa1, kbA[1], scA);
    scA = mfma32(qa2, kbA[2], scA); scA = mfma32(qa3, kbA[3], scA);
    scB = mfma32(qa0, kbB[0], scB); scB = mfma32(qa1, kbB[1], scB);
    scB = mfma32(qa2, kbB[2], scB); scB = mfma32(qa3, kbB[3], scB);
    __builtin_amdgcn_s_setprio(0);

#define SOFTMAX_PV(SC, ONES, ACC0, ACC1)                                      \
  {                                                                           \
    _Pragma("unroll")                                                         \
    for (int r = 0; r < 16; ++r) SC[r] = fexp2(SC[r]);                        \
    unsigned int a0, a1, b0, b1;                                              \
    u32x4 wv; s16x8 pa0, pa1;                                                 \
    CVTPK(a0, SC[0], SC[1]);  CVTPK(b0, SC[4], SC[5]);  PSWAP(a0, b0);        \
    CVTPK(a1, SC[2], SC[3]);  CVTPK(b1, SC[6], SC[7]);  PSWAP(a1, b1);        \
    wv[0] = a0; wv[1] = a1; wv[2] = b0; wv[3] = b1;                           \
    pa0 = __builtin_bit_cast(s16x8, wv);                                      \
    CVTPK(a0, SC[8], SC[9]);  CVTPK(b0, SC[12], SC[13]); PSWAP(a0, b0);       \
    CVTPK(a1, SC[10], SC[11]); CVTPK(b1, SC[14], SC[15]); PSWAP(a1, b1);      \
    wv[0] = a0; wv[1] = a1; wv[2] = b0; wv[3] = b1;                           \
    pa1 = __builtin_bit_cast(s16x8, wv);                                      \
    __builtin_amdgcn_s_setprio(1);                                            \
    lacc = mfma32(ONES, pa0, lacc);                                           \
    lacc = mfma32(ONES, pa1, lacc);                                           \
    ACC0 = mfma32(vb0, pa0, ACC0);                                            \
    ACC0 = mfma32(vb1, pa1, ACC0);                                            \
    ACC1 = mfma32(vb2, pa0, ACC1);                                            \
    ACC1 = mfma32(vb3, pa1, ACC1);                                            \
    __builtin_amdgcn_s_setprio(0);                                            \
  }

    SOFTMAX_PV(scA, onesA, accA0, accA1);
    SOFTMAX_PV(scB, onesB, accB0, accB1);
#undef SOFTMAX_PV

    __syncthreads();
  }

  // l extraction: lacc[0] = group A, lacc[8] = group B (halves pre-summed).
  float lA = lacc[0], lB = lacc[8];

  // merge j-partials: plain adds (no-max softmax => exact).
  float* mrg = cg ? (float*)&vb_lds[0][0][0] : (float*)&qa_lds[0][0][0];
  if (jg == 1) {
    lbuf[cg][0][lane] = lA; lbuf[cg][1][lane] = lB;
#pragma unroll
    for (int r = 0; r < 16; ++r) {
      mrg[(r)*64 + lane]      = accA0[r];
      mrg[(16 + r)*64 + lane] = accA1[r];
      mrg[(32 + r)*64 + lane] = accB0[r];
      mrg[(48 + r)*64 + lane] = accB1[r];
    }
  }
  __syncthreads();
  if (jg == 0) {
    lA += lbuf[cg][0][lane]; lB += lbuf[cg][1][lane];
#pragma unroll
    for (int r = 0; r < 16; ++r) {
      accA0[r] += mrg[(r)*64 + lane];
      accA1[r] += mrg[(16 + r)*64 + lane];
      accB0[r] += mrg[(32 + r)*64 + lane];
      accB1[r] += mrg[(48 + r)*64 + lane];
    }
    const float invA = 1.0f / lA, invB = 1.0f / lB;
    unsigned short* obaseA =
        aout + ((size_t)bh * 2048 + c0 + cg*64 + ln) * 64 + hh * 4;
    unsigned short* obaseB = obaseA + 32 * 64;
#pragma unroll
    for (int dt = 0; dt < 2; ++dt)
#pragma unroll
      for (int rq = 0; rq < 4; ++rq) {
        u16x4 pkA, pkB;
#pragma unroll
        for (int i = 0; i < 4; ++i) {
          const int reg = rq*4 + i;
          pkA[i] = f2bf(((dt == 0) ? accA0[reg] : accA1[reg]) * invA);
          pkB[i] = f2bf(((dt == 0) ? accB0[reg] : accB1[reg]) * invB);
        }
        *(u16x4*)(obaseA + dt*32 + rq*8) = pkA;
        *(u16x4*)(obaseB + dt*32 + rq*8) = pkB;
      }
  }
}

// ---------------------------------------------------------------------------
extern "C" void kernel_launch(void* const* d_in, const int* in_sizes, int n_in,
                              void* d_out, int out_size, void* d_ws, size_t ws_size,
                              hipStream_t stream) {
  (void)in_sizes; (void)n_in; (void)out_size; (void)ws_size;
  const float* k  = (const float*)d_in[0];
  const float* q  = (const float*)d_in[1];
  const float* v  = (const float*)d_in[2];
  const float* Wk = (const float*)d_in[3];
  const float* bk = (const float*)d_in[4];
  const float* Wq = (const float*)d_in[5];
  const float* bq = (const float*)d_in[6];
  const float* Wv = (const float*)d_in[7];
  const float* bv = (const float*)d_in[8];
  const float* Wo = (const float*)d_in[9];
  const float* bo = (const float*)d_in[10];

  char* ws = (char*)d_ws;
  const size_t MB = 1024 * 1024;
  unsigned short* Wkt = (unsigned short*)(ws + 0*MB);
  unsigned short* Wqt = (unsigned short*)(ws + 2*MB);
  unsigned short* Wvt = (unsigned short*)(ws + 4*MB);
  unsigned short* Wot = (unsigned short*)(ws + 6*MB);
  unsigned short* kp  = (unsigned short*)(ws + 8*MB);
  unsigned short* qp  = (unsigned short*)(ws + 16*MB);
  unsigned short* vpt = (unsigned short*)(ws + 24*MB);
  unsigned short* vc  = (unsigned short*)(ws + 32*MB);
  unsigned short* aoutb = (unsigned short*)(ws + 40*MB);  // [b][h][s][64] bf16
  unsigned short* kc = (unsigned short*)d_out;
  unsigned short* qc = (unsigned short*)((char*)d_out + 8*MB);

  PrepArgs pa;
  pa.x[0] = k; pa.x[1] = q; pa.x[2] = v;
  pa.y[0] = kc; pa.y[1] = qc; pa.y[2] = vc;
  pa.W[0] = Wk; pa.W[1] = Wq; pa.W[2] = Wv; pa.W[3] = Wo;
  pa.Wt[0] = Wkt; pa.Wt[1] = Wqt; pa.Wt[2] = Wvt; pa.Wt[3] = Wot;
  prep_kernel<<<dim3(2048, 7), 256, 0, stream>>>(pa);

  GemArgs gp;
  gp.A[0] = kc; gp.A[1] = qc; gp.A[2] = vc;
  gp.Wt[0] = Wkt; gp.Wt[1] = Wqt; gp.Wt[2] = Wvt;
  gp.bias[0] = bk; gp.bias[1] = bq; gp.bias[2] = bv;
  gp.C[0] = kp; gp.C[1] = qp; gp.C[2] = vpt;
  gp.mode[0] = 0; gp.mode[1] = 0; gp.mode[2] = 1;
  gp.scale[0] = 1.4426950408889634f;   // log2(e) folded into kp
  gp.scale[1] = 1.0f; gp.scale[2] = 1.0f;
  gemm_kernel<128, 128><<<dim3(8, 32, 3), 256, 0, stream>>>(gp);

  attn_kernel<<<dim3(512), 256, 0, stream>>>(kp, qp, vpt, aoutb);

  GemArgs gf;
  gf.A[0] = aoutb; gf.A[1] = aoutb; gf.A[2] = aoutb;
  gf.Wt[0] = Wot; gf.Wt[1] = Wot; gf.Wt[2] = Wot;
  gf.bias[0] = bo; gf.bias[1] = bo; gf.bias[2] = bo;
  gf.C[0] = d_out; gf.C[1] = d_out; gf.C[2] = d_out;
  gf.mode[0] = 2; gf.mode[1] = 2; gf.mode[2] = 2;
  gf.scale[0] = 1.0f; gf.scale[1] = 1.0f; gf.scale[2] = 1.0f;
  gemm_kernel<64, 64><<<dim3(16, 64, 1), 256, 0, stream>>>(gf);
}